// Round 6
// baseline (27.599 us; speedup 1.0000x reference)
//
#include <hip/hip_runtime.h>

#define NOUT 10
#define SIG_DIM 584   // 8 + 64 + 512
#define TPAD 68       // 64 steps + pad; col bank stride (i*68)%32 = 4i

__device__ __forceinline__ float rdlane(float x, int lane) {
    return __int_as_float(__builtin_amdgcn_readlane(__float_as_int(x), lane));
}

// 4 waves/block = 2 batches x 2 time-chunks (64 increments each); grid 1024.
// 4096 waves -> 4 waves/SIMD (2x r5's occupancy), serial chain halved.
// Lane l=(i,j): i=l>>3, j=l&7. State: S3[i][j][0..7], S2[i][j], S1[i], S1[j].
// Row broadcast: v_readlane from prepass regs (lane 2s: row s cols 0-3,
// lane 2s+1: cols 4-7 within a 32-row section) -- zero LDS traffic.
// Per-lane dxi/dxj: transposed padded LDS columns (conflict-free).
// Chunk fold: publish k-major S3 (stride-1 b32 = 2-way = free; r4's 16-way
// conflict layout was the regression), symmetric all-wave fold, no early ret.
__global__ __launch_bounds__(256) void sig_linear_kernel(
    const float* __restrict__ X, const float* __restrict__ W,
    const float* __restrict__ bias, float* __restrict__ out)
{
    __shared__ float s_dxT[4][8 * TPAD];   // per-wave transposed dX chunk
    __shared__ float s_sig[4][SIG_DIM];    // per-wave chunk signature

    const int tid = threadIdx.x;
    const int w = tid >> 6;          // wave 0..3
    const int l = tid & 63;
    const int i = l >> 3;
    const int j = l & 7;
    const int p = w >> 1;            // batch within block
    const int ch = w & 1;            // chunk: 0 = steps 0..63, 1 = 64..127
    const int b = blockIdx.x * 2 + p;

    const float* Xb = X + (size_t)b * 1024;
    float* dxT = &s_dxT[w][0];
    const int cb = (l & 1) * 4;      // this lane's 4-col segment
    const int rl = l >> 1;           // row within 32-row section
    const int R0 = ch * 64;          // first increment row of this chunk

    // Prepass: dX rows (R0 + QQ*32 + rl) -> regs (readlane source) + transposed
    // LDS (per-lane column reads). Row 127 is zeroed. Loads lane-coalesced.
    float4 dA, dB;
#define PREP(DQ, QQ)                                                          \
    {                                                                         \
        const int r  = R0 + (QQ) * 32 + rl;                                   \
        const int lr = (QQ) * 32 + rl;                                        \
        const float* xr = Xb + r * 8 + cb;                                    \
        const float4 a  = *reinterpret_cast<const float4*>(xr);               \
        const float4 c4 = *reinterpret_cast<const float4*>(xr + (r < 127 ? 8 : 0)); \
        DQ.x = (r < 127) ? c4.x - a.x : 0.f;                                  \
        DQ.y = (r < 127) ? c4.y - a.y : 0.f;                                  \
        DQ.z = (r < 127) ? c4.z - a.z : 0.f;                                  \
        DQ.w = (r < 127) ? c4.w - a.w : 0.f;                                  \
        dxT[(cb + 0) * TPAD + lr] = DQ.x;                                     \
        dxT[(cb + 1) * TPAD + lr] = DQ.y;                                     \
        dxT[(cb + 2) * TPAD + lr] = DQ.z;                                     \
        dxT[(cb + 3) * TPAD + lr] = DQ.w;                                     \
    }
    PREP(dA, 0) PREP(dB, 1)
#undef PREP
    __syncthreads();   // cross-lane LDS reads below need a real barrier

    float s3[8];
#pragma unroll
    for (int k = 0; k < 8; ++k) s3[k] = 0.f;
    float s2 = 0.f, s1i = 0.f, s1j = 0.f;

    const float* icol = dxT + i * TPAD;    // broadcast, conflict-free banks
    const float* jcol = dxT + j * TPAD;

#define STEP(DQ, LB, DXI, DXJ)                                                \
    {                                                                         \
        const float k0 = rdlane(DQ.x, (LB));                                  \
        const float k1 = rdlane(DQ.y, (LB));                                  \
        const float k2 = rdlane(DQ.z, (LB));                                  \
        const float k3 = rdlane(DQ.w, (LB));                                  \
        const float k4 = rdlane(DQ.x, (LB) + 1);                              \
        const float k5 = rdlane(DQ.y, (LB) + 1);                              \
        const float k6 = rdlane(DQ.z, (LB) + 1);                              \
        const float k7 = rdlane(DQ.w, (LB) + 1);                              \
        const float cc = (DXI) * (DXJ);                                       \
        const float uu = s1i * (DXJ);                                         \
        const float f  = fmaf(0.5f, uu, fmaf(1.0f / 6.0f, cc, s2));           \
        s3[0] = fmaf(f, k0, s3[0]);                                           \
        s3[1] = fmaf(f, k1, s3[1]);                                           \
        s3[2] = fmaf(f, k2, s3[2]);                                           \
        s3[3] = fmaf(f, k3, s3[3]);                                           \
        s3[4] = fmaf(f, k4, s3[4]);                                           \
        s3[5] = fmaf(f, k5, s3[5]);                                           \
        s3[6] = fmaf(f, k6, s3[6]);                                           \
        s3[7] = fmaf(f, k7, s3[7]);                                           \
        s2 = fmaf(0.5f, cc, s2 + uu);                                         \
        s1i += (DXI);                                                         \
        s1j += (DXJ);                                                         \
    }

    // One 32-row section: 8 groups of 4 steps; readlane base = g*8.
#define SECTION(DQ, QQ)                                                       \
    for (int g = 0; g < 8; ++g) {                                             \
        const int t0 = (QQ) * 32 + g * 4;                                     \
        const float4 ic = *reinterpret_cast<const float4*>(icol + t0);        \
        const float4 jc = *reinterpret_cast<const float4*>(jcol + t0);        \
        const int lb = g * 8;                                                 \
        STEP(DQ, lb + 0, ic.x, jc.x)                                          \
        STEP(DQ, lb + 2, ic.y, jc.y)                                          \
        STEP(DQ, lb + 4, ic.z, jc.z)                                          \
        STEP(DQ, lb + 6, ic.w, jc.w)                                          \
    }
    SECTION(dA, 0)
    SECTION(dB, 1)
#undef SECTION
#undef STEP

    // Publish this chunk's signature. S3 k-major: [72 + k*64 + l] -- stride-1
    // across lanes per instruction (2-way bank alias = free).
    {
        float* sg = s_sig[w];
        if (i == 0) sg[j] = s1j;           // lanes (0,j) hold S1[j]
        sg[8 + l] = s2;
#pragma unroll
        for (int k = 0; k < 8; ++k) sg[72 + k * 64 + l] = s3[k];
    }
    __syncthreads();

    // Both waves of the pair fold chunks 0,1 identically from zero state.
    //   S3 += S2a[ij]*S1b[k] + S1a[i]*S2b[jk] + S3b[ijk]
    //   S2 += S1a[i]*S1b[j] + S2b[ij];  S1 += S1b
#pragma unroll
    for (int k = 0; k < 8; ++k) s3[k] = 0.f;
    s2 = 0.f; s1i = 0.f; s1j = 0.f;
#pragma unroll
    for (int c = 0; c < 2; ++c) {
        const float* sg = s_sig[p * 2 + c];
        const float4 b0 = *reinterpret_cast<const float4*>(sg);      // S1b[0..3]
        const float4 b1 = *reinterpret_cast<const float4*>(sg + 4);  // S1b[4..7]
        const float s1bi = sg[i];
        const float s1bj = sg[j];
        const float s2b = sg[8 + l];
        const float4 q0 = *reinterpret_cast<const float4*>(sg + 8 + j * 8);     // S2b[j][0-3]
        const float4 q1 = *reinterpret_cast<const float4*>(sg + 8 + j * 8 + 4); // S2b[j][4-7]
        float tb[8];
#pragma unroll
        for (int k = 0; k < 8; ++k) tb[k] = sg[72 + k * 64 + l];
        s3[0] = fmaf(s2, b0.x, fmaf(s1i, q0.x, s3[0] + tb[0]));
        s3[1] = fmaf(s2, b0.y, fmaf(s1i, q0.y, s3[1] + tb[1]));
        s3[2] = fmaf(s2, b0.z, fmaf(s1i, q0.z, s3[2] + tb[2]));
        s3[3] = fmaf(s2, b0.w, fmaf(s1i, q0.w, s3[3] + tb[3]));
        s3[4] = fmaf(s2, b1.x, fmaf(s1i, q1.x, s3[4] + tb[4]));
        s3[5] = fmaf(s2, b1.y, fmaf(s1i, q1.y, s3[5] + tb[5]));
        s3[6] = fmaf(s2, b1.z, fmaf(s1i, q1.z, s3[6] + tb[6]));
        s3[7] = fmaf(s2, b1.w, fmaf(s1i, q1.w, s3[7] + tb[7]));
        s2 = s2 + fmaf(s1i, s1bj, s2b);
        s1i += s1bi;
        s1j += s1bj;
    }

    // Epilogue: wave pair splits outputs -- chunk0 wave: o even, chunk1: o odd.
    for (int o = ch; o < NOUT; o += 2) {
        const float* wrow = W + o * SIG_DIM;
        float part = s2 * wrow[8 + l];
        const float4 w0 = *reinterpret_cast<const float4*>(wrow + 72 + l * 8);
        const float4 w1 = *reinterpret_cast<const float4*>(wrow + 72 + l * 8 + 4);
        part = fmaf(s3[0], w0.x, part); part = fmaf(s3[1], w0.y, part);
        part = fmaf(s3[2], w0.z, part); part = fmaf(s3[3], w0.w, part);
        part = fmaf(s3[4], w1.x, part); part = fmaf(s3[5], w1.y, part);
        part = fmaf(s3[6], w1.z, part); part = fmaf(s3[7], w1.w, part);
        if (i == 0) part = fmaf(s1j, wrow[j], part);   // S1 contribution
#pragma unroll
        for (int off = 32; off > 0; off >>= 1) part += __shfl_xor(part, off);
        if (l == 0) out[b * NOUT + o] = part + bias[o];
    }
}

extern "C" void kernel_launch(void* const* d_in, const int* in_sizes, int n_in,
                              void* d_out, int out_size, void* d_ws, size_t ws_size,
                              hipStream_t stream) {
    const float* X = (const float*)d_in[0];     // (2048, 128, 8)
    const float* W = (const float*)d_in[1];     // (10, 584)
    const float* bias = (const float*)d_in[2];  // (10,)
    float* out = (float*)d_out;                 // (2048, 10)
    sig_linear_kernel<<<dim3(1024), dim3(256), 0, stream>>>(X, W, bias, out);
}

// Round 7
// 27.480 us; speedup vs baseline: 1.0043x; 1.0043x over previous
//
#include <hip/hip_runtime.h>

#define NOUT 10
#define SIG_DIM 584   // 8 + 64 + 512
#define TPAD 68       // 64 steps + pad; col bank stride (i*68)%32 = 4i

__device__ __forceinline__ float rdlane(float x, int lane) {
    return __int_as_float(__builtin_amdgcn_readlane(__float_as_int(x), lane));
}

// 4 waves/block = 2 batches x 2 time-chunks (64 increments each); grid 1024.
// 4096 waves -> 4 waves/SIMD (2x r5's occupancy), serial chain halved.
// Lane l=(i,j): i=l>>3, j=l&7. State: S3[i][j][0..7], S2[i][j], S1[i], S1[j].
// Row broadcast: v_readlane from prepass regs (lane 2s: row s cols 0-3,
// lane 2s+1: cols 4-7 within a 32-row section) -- zero LDS traffic.
// Per-lane dxi/dxj: transposed padded LDS columns (conflict-free).
// Chunk fold: publish k-major S3 (stride-1 b32 = 2-way = free; r4's 16-way
// conflict layout was the regression), symmetric all-wave fold, no early ret.
__global__ __launch_bounds__(256) void sig_linear_kernel(
    const float* __restrict__ X, const float* __restrict__ W,
    const float* __restrict__ bias, float* __restrict__ out)
{
    __shared__ float s_dxT[4][8 * TPAD];   // per-wave transposed dX chunk
    __shared__ float s_sig[4][SIG_DIM];    // per-wave chunk signature

    const int tid = threadIdx.x;
    const int w = tid >> 6;          // wave 0..3
    const int l = tid & 63;
    const int i = l >> 3;
    const int j = l & 7;
    const int p = w >> 1;            // batch within block
    const int ch = w & 1;            // chunk: 0 = steps 0..63, 1 = 64..127
    const int b = blockIdx.x * 2 + p;

    const float* Xb = X + (size_t)b * 1024;
    float* dxT = &s_dxT[w][0];
    const int cb = (l & 1) * 4;      // this lane's 4-col segment
    const int rl = l >> 1;           // row within 32-row section
    const int R0 = ch * 64;          // first increment row of this chunk

    // Prepass: dX rows (R0 + QQ*32 + rl) -> regs (readlane source) + transposed
    // LDS (per-lane column reads). Row 127 is zeroed. Loads lane-coalesced.
    float4 dA, dB;
#define PREP(DQ, QQ)                                                          \
    {                                                                         \
        const int r  = R0 + (QQ) * 32 + rl;                                   \
        const int lr = (QQ) * 32 + rl;                                        \
        const float* xr = Xb + r * 8 + cb;                                    \
        const float4 a  = *reinterpret_cast<const float4*>(xr);               \
        const float4 c4 = *reinterpret_cast<const float4*>(xr + (r < 127 ? 8 : 0)); \
        DQ.x = (r < 127) ? c4.x - a.x : 0.f;                                  \
        DQ.y = (r < 127) ? c4.y - a.y : 0.f;                                  \
        DQ.z = (r < 127) ? c4.z - a.z : 0.f;                                  \
        DQ.w = (r < 127) ? c4.w - a.w : 0.f;                                  \
        dxT[(cb + 0) * TPAD + lr] = DQ.x;                                     \
        dxT[(cb + 1) * TPAD + lr] = DQ.y;                                     \
        dxT[(cb + 2) * TPAD + lr] = DQ.z;                                     \
        dxT[(cb + 3) * TPAD + lr] = DQ.w;                                     \
    }
    PREP(dA, 0) PREP(dB, 1)
#undef PREP
    __syncthreads();   // cross-lane LDS reads below need a real barrier

    float s3[8];
#pragma unroll
    for (int k = 0; k < 8; ++k) s3[k] = 0.f;
    float s2 = 0.f, s1i = 0.f, s1j = 0.f;

    const float* icol = dxT + i * TPAD;    // broadcast, conflict-free banks
    const float* jcol = dxT + j * TPAD;

#define STEP(DQ, LB, DXI, DXJ)                                                \
    {                                                                         \
        const float k0 = rdlane(DQ.x, (LB));                                  \
        const float k1 = rdlane(DQ.y, (LB));                                  \
        const float k2 = rdlane(DQ.z, (LB));                                  \
        const float k3 = rdlane(DQ.w, (LB));                                  \
        const float k4 = rdlane(DQ.x, (LB) + 1);                              \
        const float k5 = rdlane(DQ.y, (LB) + 1);                              \
        const float k6 = rdlane(DQ.z, (LB) + 1);                              \
        const float k7 = rdlane(DQ.w, (LB) + 1);                              \
        const float cc = (DXI) * (DXJ);                                       \
        const float uu = s1i * (DXJ);                                         \
        const float f  = fmaf(0.5f, uu, fmaf(1.0f / 6.0f, cc, s2));           \
        s3[0] = fmaf(f, k0, s3[0]);                                           \
        s3[1] = fmaf(f, k1, s3[1]);                                           \
        s3[2] = fmaf(f, k2, s3[2]);                                           \
        s3[3] = fmaf(f, k3, s3[3]);                                           \
        s3[4] = fmaf(f, k4, s3[4]);                                           \
        s3[5] = fmaf(f, k5, s3[5]);                                           \
        s3[6] = fmaf(f, k6, s3[6]);                                           \
        s3[7] = fmaf(f, k7, s3[7]);                                           \
        s2 = fmaf(0.5f, cc, s2 + uu);                                         \
        s1i += (DXI);                                                         \
        s1j += (DXJ);                                                         \
    }

    // One 32-row section: 8 groups of 4 steps; readlane base = g*8.
#define SECTION(DQ, QQ)                                                       \
    for (int g = 0; g < 8; ++g) {                                             \
        const int t0 = (QQ) * 32 + g * 4;                                     \
        const float4 ic = *reinterpret_cast<const float4*>(icol + t0);        \
        const float4 jc = *reinterpret_cast<const float4*>(jcol + t0);        \
        const int lb = g * 8;                                                 \
        STEP(DQ, lb + 0, ic.x, jc.x)                                          \
        STEP(DQ, lb + 2, ic.y, jc.y)                                          \
        STEP(DQ, lb + 4, ic.z, jc.z)                                          \
        STEP(DQ, lb + 6, ic.w, jc.w)                                          \
    }
    SECTION(dA, 0)
    SECTION(dB, 1)
#undef SECTION
#undef STEP

    // Publish this chunk's signature. S3 k-major: [72 + k*64 + l] -- stride-1
    // across lanes per instruction (2-way bank alias = free).
    {
        float* sg = s_sig[w];
        if (i == 0) sg[j] = s1j;           // lanes (0,j) hold S1[j]
        sg[8 + l] = s2;
#pragma unroll
        for (int k = 0; k < 8; ++k) sg[72 + k * 64 + l] = s3[k];
    }
    __syncthreads();

    // Both waves of the pair fold chunks 0,1 identically from zero state.
    //   S3 += S2a[ij]*S1b[k] + S1a[i]*S2b[jk] + S3b[ijk]
    //   S2 += S1a[i]*S1b[j] + S2b[ij];  S1 += S1b
#pragma unroll
    for (int k = 0; k < 8; ++k) s3[k] = 0.f;
    s2 = 0.f; s1i = 0.f; s1j = 0.f;
#pragma unroll
    for (int c = 0; c < 2; ++c) {
        const float* sg = s_sig[p * 2 + c];
        const float4 b0 = *reinterpret_cast<const float4*>(sg);      // S1b[0..3]
        const float4 b1 = *reinterpret_cast<const float4*>(sg + 4);  // S1b[4..7]
        const float s1bi = sg[i];
        const float s1bj = sg[j];
        const float s2b = sg[8 + l];
        const float4 q0 = *reinterpret_cast<const float4*>(sg + 8 + j * 8);     // S2b[j][0-3]
        const float4 q1 = *reinterpret_cast<const float4*>(sg + 8 + j * 8 + 4); // S2b[j][4-7]
        float tb[8];
#pragma unroll
        for (int k = 0; k < 8; ++k) tb[k] = sg[72 + k * 64 + l];
        s3[0] = fmaf(s2, b0.x, fmaf(s1i, q0.x, s3[0] + tb[0]));
        s3[1] = fmaf(s2, b0.y, fmaf(s1i, q0.y, s3[1] + tb[1]));
        s3[2] = fmaf(s2, b0.z, fmaf(s1i, q0.z, s3[2] + tb[2]));
        s3[3] = fmaf(s2, b0.w, fmaf(s1i, q0.w, s3[3] + tb[3]));
        s3[4] = fmaf(s2, b1.x, fmaf(s1i, q1.x, s3[4] + tb[4]));
        s3[5] = fmaf(s2, b1.y, fmaf(s1i, q1.y, s3[5] + tb[5]));
        s3[6] = fmaf(s2, b1.z, fmaf(s1i, q1.z, s3[6] + tb[6]));
        s3[7] = fmaf(s2, b1.w, fmaf(s1i, q1.w, s3[7] + tb[7]));
        s2 = s2 + fmaf(s1i, s1bj, s2b);
        s1i += s1bi;
        s1j += s1bj;
    }

    // Epilogue: wave pair splits outputs -- chunk0 wave: o even, chunk1: o odd.
    for (int o = ch; o < NOUT; o += 2) {
        const float* wrow = W + o * SIG_DIM;
        float part = s2 * wrow[8 + l];
        const float4 w0 = *reinterpret_cast<const float4*>(wrow + 72 + l * 8);
        const float4 w1 = *reinterpret_cast<const float4*>(wrow + 72 + l * 8 + 4);
        part = fmaf(s3[0], w0.x, part); part = fmaf(s3[1], w0.y, part);
        part = fmaf(s3[2], w0.z, part); part = fmaf(s3[3], w0.w, part);
        part = fmaf(s3[4], w1.x, part); part = fmaf(s3[5], w1.y, part);
        part = fmaf(s3[6], w1.z, part); part = fmaf(s3[7], w1.w, part);
        if (i == 0) part = fmaf(s1j, wrow[j], part);   // S1 contribution
#pragma unroll
        for (int off = 32; off > 0; off >>= 1) part += __shfl_xor(part, off);
        if (l == 0) out[b * NOUT + o] = part + bias[o];
    }
}

extern "C" void kernel_launch(void* const* d_in, const int* in_sizes, int n_in,
                              void* d_out, int out_size, void* d_ws, size_t ws_size,
                              hipStream_t stream) {
    const float* X = (const float*)d_in[0];     // (2048, 128, 8)
    const float* W = (const float*)d_in[1];     // (10, 584)
    const float* bias = (const float*)d_in[2];  // (10,)
    float* out = (float*)d_out;                 // (2048, 10)
    sig_linear_kernel<<<dim3(1024), dim3(256), 0, stream>>>(X, W, bias, out);
}

// Round 8
// 21.485 us; speedup vs baseline: 1.2846x; 1.2791x over previous
//
#include <hip/hip_runtime.h>

#define NOUT 10
#define SIG_DIM 584   // 8 + 64 + 512
#define TPAD 132      // padded T-stride: (i*TPAD)%32 = 4i -> conflict-free cols

__device__ __forceinline__ float rdlane(float x, int lane) {
    return __int_as_float(__builtin_amdgcn_readlane(__float_as_int(x), lane));
}

// 4 waves/block, ONE batch element per wave (512 blocks; 2 waves/SIMD).
// Full 127-step serial recurrence per wave -- no chunk fold (r6 regression).
// Lane l=(i,j): i=l>>3, j=l&7. State: S3[i][j][0..7], S2[i][j], S1[i], S1[j].
// Row broadcast: v_readlane from prepass regs dA..dD (lane 2r: section-row r
// cols 0-3, lane 2r+1: cols 4-7) -- zero LDS traffic for rows.
// Per-lane dxi/dxj: transposed padded LDS columns, DOUBLE-BUFFERED 16 steps
// ahead in registers (r5 ran at VGPR=28 -> compiler had no regs to pipeline;
// ~120cy LDS latency exposed every 4 steps was the 4x-over-issue-floor gap).
__global__ __launch_bounds__(256) void sig_linear_kernel(
    const float* __restrict__ X, const float* __restrict__ W,
    const float* __restrict__ bias, float* __restrict__ out)
{
    __shared__ float s_dxT[4][8 * TPAD];   // per-wave transposed dX (16.9 KB)

    const int tid = threadIdx.x;
    const int w = tid >> 6;
    const int l = tid & 63;
    const int i = l >> 3;
    const int j = l & 7;
    const int b = blockIdx.x * 4 + w;

    const float* Xb = X + (size_t)b * 1024;
    float* dxT = &s_dxT[w][0];
    const int cb = (l & 1) * 4;            // this lane's 4-col segment
    const int rl = l >> 1;                 // row within 32-row section

    // Prepass: dX rows q*32+rl -> regs dA..dD (readlane source) + transposed
    // LDS (per-lane column reads). Row 127 zeroed. Loads lane-coalesced.
    float4 dA, dB, dC, dD;
#define PREP(DQ, QQ)                                                          \
    {                                                                         \
        const int r = (QQ) * 32 + rl;                                         \
        const float* xr = Xb + r * 8 + cb;                                    \
        const float4 a  = *reinterpret_cast<const float4*>(xr);               \
        const float4 c4 = *reinterpret_cast<const float4*>(xr + (r < 127 ? 8 : 0)); \
        DQ.x = (r < 127) ? c4.x - a.x : 0.f;                                  \
        DQ.y = (r < 127) ? c4.y - a.y : 0.f;                                  \
        DQ.z = (r < 127) ? c4.z - a.z : 0.f;                                  \
        DQ.w = (r < 127) ? c4.w - a.w : 0.f;                                  \
        dxT[(cb + 0) * TPAD + r] = DQ.x;                                      \
        dxT[(cb + 1) * TPAD + r] = DQ.y;                                      \
        dxT[(cb + 2) * TPAD + r] = DQ.z;                                      \
        dxT[(cb + 3) * TPAD + r] = DQ.w;                                      \
    }
    PREP(dA, 0) PREP(dB, 1) PREP(dC, 2) PREP(dD, 3)
#undef PREP
    __syncthreads();   // cross-lane LDS reads below need a real barrier

    float s3[8];
#pragma unroll
    for (int k = 0; k < 8; ++k) s3[k] = 0.f;
    float s2 = 0.f, s1i = 0.f, s1j = 0.f;

    const float* icol = dxT + i * TPAD;    // conflict-free: banks 4i+t
    const float* jcol = dxT + j * TPAD;

#define STEP(DQ, LB, DXI, DXJ)                                                \
    {                                                                         \
        const float k0 = rdlane(DQ.x, (LB));                                  \
        const float k1 = rdlane(DQ.y, (LB));                                  \
        const float k2 = rdlane(DQ.z, (LB));                                  \
        const float k3 = rdlane(DQ.w, (LB));                                  \
        const float k4 = rdlane(DQ.x, (LB) + 1);                              \
        const float k5 = rdlane(DQ.y, (LB) + 1);                              \
        const float k6 = rdlane(DQ.z, (LB) + 1);                              \
        const float k7 = rdlane(DQ.w, (LB) + 1);                              \
        const float cc = (DXI) * (DXJ);                                       \
        const float uu = s1i * (DXJ);                                         \
        const float f  = fmaf(0.5f, uu, fmaf(1.0f / 6.0f, cc, s2));           \
        s3[0] = fmaf(f, k0, s3[0]);                                           \
        s3[1] = fmaf(f, k1, s3[1]);                                           \
        s3[2] = fmaf(f, k2, s3[2]);                                           \
        s3[3] = fmaf(f, k3, s3[3]);                                           \
        s3[4] = fmaf(f, k4, s3[4]);                                           \
        s3[5] = fmaf(f, k5, s3[5]);                                           \
        s3[6] = fmaf(f, k6, s3[6]);                                           \
        s3[7] = fmaf(f, k7, s3[7]);                                           \
        s2 = fmaf(0.5f, cc, s2 + uu);                                         \
        s1i += (DXI);                                                         \
        s1j += (DXJ);                                                         \
    }

    // Register double-buffer: 16 steps of both columns per buffer (32 VGPRs).
    float4 iA[4], jA[4], iB[4], jB[4];
#define LOADH(BI, BJ, T0)                                                     \
    _Pragma("unroll")                                                         \
    for (int q4 = 0; q4 < 4; ++q4) {                                          \
        BI[q4] = *reinterpret_cast<const float4*>(icol + (T0) + 4 * q4);      \
        BJ[q4] = *reinterpret_cast<const float4*>(jcol + (T0) + 4 * q4);      \
    }
    // 16 steps from buffer; readlane lane base LB0 = 32*half within section.
#define HALF(DQ, LB0, BI, BJ)                                                 \
    _Pragma("unroll")                                                         \
    for (int q4 = 0; q4 < 4; ++q4) {                                          \
        STEP(DQ, (LB0) + 8 * q4 + 0, BI[q4].x, BJ[q4].x)                      \
        STEP(DQ, (LB0) + 8 * q4 + 2, BI[q4].y, BJ[q4].y)                      \
        STEP(DQ, (LB0) + 8 * q4 + 4, BI[q4].z, BJ[q4].z)                      \
        STEP(DQ, (LB0) + 8 * q4 + 6, BI[q4].w, BJ[q4].w)                      \
    }

    LOADH(iA, jA, 0)
    LOADH(iB, jB, 16)  HALF(dA, 0,  iA, jA)     // steps   0..15
    LOADH(iA, jA, 32)  HALF(dA, 32, iB, jB)     // steps  16..31
    LOADH(iB, jB, 48)  HALF(dB, 0,  iA, jA)     // steps  32..47
    LOADH(iA, jA, 64)  HALF(dB, 32, iB, jB)     // steps  48..63
    LOADH(iB, jB, 80)  HALF(dC, 0,  iA, jA)     // steps  64..79
    LOADH(iA, jA, 96)  HALF(dC, 32, iB, jB)     // steps  80..95
    LOADH(iB, jB, 112) HALF(dD, 0,  iA, jA)     // steps  96..111
                       HALF(dD, 32, iB, jB)     // steps 112..127 (127 zeroed)
#undef HALF
#undef LOADH
#undef STEP

    // Epilogue (r1/r5-proven): out[b][o] = bias[o] + W[o][:] . sig[b][:]
    // sig layout: [0..7]=S1, [8+l]=S2[i][j], [72+l*8+k]=S3[i][j][k]
#pragma unroll
    for (int o = 0; o < NOUT; ++o) {
        const float* wrow = W + o * SIG_DIM;
        float part = s2 * wrow[8 + l];
        const float4 w0 = *reinterpret_cast<const float4*>(wrow + 72 + l * 8);
        const float4 w1 = *reinterpret_cast<const float4*>(wrow + 72 + l * 8 + 4);
        part = fmaf(s3[0], w0.x, part); part = fmaf(s3[1], w0.y, part);
        part = fmaf(s3[2], w0.z, part); part = fmaf(s3[3], w0.w, part);
        part = fmaf(s3[4], w1.x, part); part = fmaf(s3[5], w1.y, part);
        part = fmaf(s3[6], w1.z, part); part = fmaf(s3[7], w1.w, part);
        if (i == 0) part = fmaf(s1j, wrow[j], part);   // S1 contribution
#pragma unroll
        for (int off = 32; off > 0; off >>= 1) part += __shfl_xor(part, off);
        if (l == 0) out[b * NOUT + o] = part + bias[o];
    }
}

extern "C" void kernel_launch(void* const* d_in, const int* in_sizes, int n_in,
                              void* d_out, int out_size, void* d_ws, size_t ws_size,
                              hipStream_t stream) {
    const float* X = (const float*)d_in[0];     // (2048, 128, 8)
    const float* W = (const float*)d_in[1];     // (10, 584)
    const float* bias = (const float*)d_in[2];  // (10,)
    float* out = (float*)d_out;                 // (2048, 10)
    sig_linear_kernel<<<dim3(512), dim3(256), 0, stream>>>(X, W, bias, out);
}